// Round 5
// baseline (490.909 us; speedup 1.0000x reference)
//
#include <hip/hip_runtime.h>
#include <cstdint>

// DynMoleRouterLoss: gate_logits [N x 64] f32, attention_mask [maskN] i32 -> scalar f32.
// R5 = RESUBMIT of R4 measurement round (R4 hit GPUAcquisitionTimeout, no data).
// Identical compute kernel to R3, launched TWICE with a re-zero between
// (zero -> moe -> zero -> moe -> finalize). Result identical (first pass wiped);
// dur - 414us ~= T_moe, resolving whether moe_main is ~50us (roofline) or ~140us
// (headroom) -- indistinguishable from top-5 counters since every moe dispatch < 157us
// fill cutoff.
// acc layout in d_ws (floats): [0..63] m-weighted orig per-expert sums, [64..127]
// top-p corrections (rare), [128] sum(clip(w)), [129] sum(clip(w)^1.2).

static constexpr float LOG2E = 1.4426950408889634f;
static constexpr float EPS   = 1e-5f;
static constexpr float EPSQ  = 1e-6f;     // (1e-5)^1.2
static constexpr float QQ    = 1.2f;

__global__ void zero_acc(float* __restrict__ a) {
    if (threadIdx.x < 130) a[threadIdx.x] = 0.f;
}

__device__ __forceinline__
void pass_row(float4 v, float msc, bool valid, int s, int grp,
              float& ea0, float& ea1, float& ea2, float& ea3,
              float& clipA, float& clipqA, float* __restrict__ acc)
{
    float mx = fmaxf(fmaxf(v.x, v.y), fmaxf(v.z, v.w));
    #pragma unroll
    for (int sh = 1; sh < 16; sh <<= 1) mx = fmaxf(mx, __shfl_xor(mx, sh, 16));

    float mxl = mx * LOG2E;
    float t0 = __fmaf_rn(v.x, LOG2E, -mxl);
    float t1 = __fmaf_rn(v.y, LOG2E, -mxl);
    float t2 = __fmaf_rn(v.z, LOG2E, -mxl);
    float t3 = __fmaf_rn(v.w, LOG2E, -mxl);
    float x0 = __builtin_amdgcn_exp2f(t0);
    float x1 = __builtin_amdgcn_exp2f(t1);
    float x2 = __builtin_amdgcn_exp2f(t2);
    float x3 = __builtin_amdgcn_exp2f(t3);

    float z = (x0 + x1) + (x2 + x3);
    #pragma unroll
    for (int sh = 1; sh < 16; sh <<= 1) z += __shfl_xor(z, sh, 16);

    float lz = __builtin_amdgcn_logf(z);               // log2(z)
    float rz = __builtin_amdgcn_exp2f(-lz);            // 1/z (no div sequence)
    float zq = __builtin_amdgcn_exp2f(-QQ * lz);       // z^-1.2

    float w0 = x0*rz, w1 = x1*rz, w2 = x2*rz, w3 = x3*rz;
    float c0 = fmaxf(w0, EPS), c1 = fmaxf(w1, EPS);
    float c2 = fmaxf(w2, EPS), c3 = fmaxf(w3, EPS);
    float q0 = fmaxf(__builtin_amdgcn_exp2f(QQ*t0)*zq, EPSQ);
    float q1 = fmaxf(__builtin_amdgcn_exp2f(QQ*t1)*zq, EPSQ);
    float q2 = fmaxf(__builtin_amdgcn_exp2f(QQ*t2)*zq, EPSQ);
    float q3 = fmaxf(__builtin_amdgcn_exp2f(QQ*t3)*zq, EPSQ);

    float rcl = (c0+c1)+(c2+c3);
    float rql = (q0+q1)+(q2+q3);
    if (valid) { clipA += rcl; clipqA += rql; }

    float rcq = rql;
    #pragma unroll
    for (int sh = 1; sh < 16; sh <<= 1) rcq += __shfl_xor(rcq, sh, 16);

    ea0 = __fmaf_rn(w0, msc, ea0);
    ea1 = __fmaf_rn(w1, msc, ea1);
    ea2 = __fmaf_rn(w2, msc, ea2);
    ea3 = __fmaf_rn(w3, msc, ea3);

    // rare path screen: flag needs rcq >= 0.7 * rc^1.2 and rc >= 1
    bool pre = valid && (msc != 0.f) && (rcq >= 0.699f);
    unsigned long long balpre = __ballot(pre ? 1 : 0);
    if (balpre) {
        float rc = rcl;
        #pragma unroll
        for (int sh = 1; sh < 16; sh <<= 1) rc += __shfl_xor(rc, sh, 16);
        float ent = (1.f - rcq * __builtin_amdgcn_exp2f(-QQ * __builtin_amdgcn_logf(rc))) * 5.f;
        bool flag = pre && (ent < 1.5f);
        unsigned long long bal = __ballot(flag ? 1 : 0);
        #pragma unroll 1
        for (int g = 0; g < 4; ++g) {
            if ((bal >> (g * 16)) & 0xFFFFull) {
                if (grp == g) {
                    float wl[4] = {w0, w1, w2, w3};
                    int   rank[4] = {0, 0, 0, 0};
                    float cum[4]  = {wl[0], wl[1], wl[2], wl[3]};
                    int base4 = s << 2;
                    #pragma unroll 1
                    for (int j = 0; j < 16; ++j) {
                        float uj[4];
                        uj[0] = __shfl(w0, j, 16);
                        uj[1] = __shfl(w1, j, 16);
                        uj[2] = __shfl(w2, j, 16);
                        uj[3] = __shfl(w3, j, 16);
                        #pragma unroll
                        for (int m = 0; m < 4; ++m) {
                            int ej = (j << 2) + m;
                            #pragma unroll
                            for (int k = 0; k < 4; ++k) {
                                int ek = base4 + k;
                                bool before = (uj[m] > wl[k]) || (uj[m] == wl[k] && ej < ek);
                                if (before) { rank[k]++; cum[k] += uj[m]; }
                            }
                        }
                    }
                    #pragma unroll
                    for (int k = 0; k < 4; ++k)
                        if (cum[k] > 0.75f && rank[k] >= 2)
                            atomicAdd(&acc[64 + base4 + k], wl[k]);   // mscale==1 here
                }
            }
        }
    }
}

#define LOAD_TILE(V0, V1, V2, V3, M, RB) do {                                   \
    long long r0_ = (RB)+0 < N ? (RB)+0 : N-1;                                  \
    long long r1_ = (RB)+1 < N ? (RB)+1 : N-1;                                  \
    long long r2_ = (RB)+2 < N ? (RB)+2 : N-1;                                  \
    long long r3_ = (RB)+3 < N ? (RB)+3 : N-1;                                  \
    V0 = *((const float4*)(G + (r0_ << 6)) + s);                                \
    V1 = *((const float4*)(G + (r1_ << 6)) + s);                                \
    V2 = *((const float4*)(G + (r2_ << 6)) + s);                                \
    V3 = *((const float4*)(G + (r3_ << 6)) + s);                                \
    long long mr_ = (RB) < N ? (RB) : N-1;                                      \
    int mi_ = maskPow2 ? (int)(mr_ & (long long)(maskN-1))                      \
                       : (int)(mr_ % (long long)maskN);                         \
    mi_ &= ~3;                                                                  \
    M = *(const int4*)(am + mi_);                                               \
} while (0)

__global__ __launch_bounds__(256)
void moe_main(const float* __restrict__ G, const int* __restrict__ am,
              long long N, int maskN, int maskPow2, float* __restrict__ acc)
{
    __shared__ float sm[4][66];
    const int t    = threadIdx.x;
    const int lane = t & 63;
    const int wv   = t >> 6;
    const int s    = lane & 15;   // expert quad: experts 4s..4s+3
    const int grp  = lane >> 4;
    const long long tiles = (N + 63) >> 6;              // 64 rows per block-tile
    const long long roff  = (long long)(wv * 16 + grp * 4);
    const long long gstep = (long long)gridDim.x;

    float ea0=0.f, ea1=0.f, ea2=0.f, ea3=0.f, clipA=0.f, clipqA=0.f;

    long long tl = blockIdx.x;
    if (tl < tiles) {
        long long rb = tl * 64 + roff;
        float4 Av0, Av1, Av2, Av3; int4 Am;
        LOAD_TILE(Av0, Av1, Av2, Av3, Am, rb);

        while (tl < tiles) {
            long long tn  = tl + gstep;
            long long tnc = (tn < tiles) ? tn : tl;     // last iter: harmless reload
            long long rbn = tnc * 64 + roff;

            // issue next tile's loads BEFORE computing current (latency hidden)
            float4 Bv0, Bv1, Bv2, Bv3; int4 Bm;
            LOAD_TILE(Bv0, Bv1, Bv2, Bv3, Bm, rbn);

            pass_row(Av0, (rb+0 < N) ? (float)Am.x : 0.f, rb+0 < N, s, grp,
                     ea0, ea1, ea2, ea3, clipA, clipqA, acc);
            pass_row(Av1, (rb+1 < N) ? (float)Am.y : 0.f, rb+1 < N, s, grp,
                     ea0, ea1, ea2, ea3, clipA, clipqA, acc);
            pass_row(Av2, (rb+2 < N) ? (float)Am.z : 0.f, rb+2 < N, s, grp,
                     ea0, ea1, ea2, ea3, clipA, clipqA, acc);
            pass_row(Av3, (rb+3 < N) ? (float)Am.w : 0.f, rb+3 < N, s, grp,
                     ea0, ea1, ea2, ea3, clipA, clipqA, acc);

            Av0 = Bv0; Av1 = Bv1; Av2 = Bv2; Av3 = Bv3; Am = Bm;
            rb = rbn; tl = tn;
        }
    }

    // epilogue: reduce per-expert sums across the 4 row-groups of each wave
    ea0 += __shfl_xor(ea0, 16, 64); ea0 += __shfl_xor(ea0, 32, 64);
    ea1 += __shfl_xor(ea1, 16, 64); ea1 += __shfl_xor(ea1, 32, 64);
    ea2 += __shfl_xor(ea2, 16, 64); ea2 += __shfl_xor(ea2, 32, 64);
    ea3 += __shfl_xor(ea3, 16, 64); ea3 += __shfl_xor(ea3, 32, 64);
    #pragma unroll
    for (int sh = 1; sh <= 32; sh <<= 1) {
        clipA  += __shfl_xor(clipA,  sh, 64);
        clipqA += __shfl_xor(clipqA, sh, 64);
    }
    if (grp == 0) {
        sm[wv][(s << 2) + 0] = ea0;
        sm[wv][(s << 2) + 1] = ea1;
        sm[wv][(s << 2) + 2] = ea2;
        sm[wv][(s << 2) + 3] = ea3;
    }
    if (lane == 0) { sm[wv][64] = clipA; sm[wv][65] = clipqA; }
    __syncthreads();
    if (t < 64) {
        float v = (sm[0][t] + sm[1][t]) + (sm[2][t] + sm[3][t]);
        atomicAdd(&acc[t], v);
    }
    if (t == 0) {
        atomicAdd(&acc[128], (sm[0][64] + sm[1][64]) + (sm[2][64] + sm[3][64]));
        atomicAdd(&acc[129], (sm[0][65] + sm[1][65]) + (sm[2][65] + sm[3][65]));
    }
}

__global__ void finalize(const float* __restrict__ acc, const int* __restrict__ am,
                         int maskN, int layers, float* __restrict__ out) {
    __shared__ float red[256];
    int t = threadIdx.x;

    float ms = 0.f;
    for (int i = t; i < maskN; i += 256) ms += (float)am[i];
    red[t] = ms; __syncthreads();
    for (int s = 128; s >= 1; s >>= 1) { if (t < s) red[t] += red[t + s]; __syncthreads(); }
    float denom = red[0] * (float)layers;
    __syncthreads();

    float p = 0.f;
    if (t < 64) {
        float o   = acc[t];
        float tok = o - acc[64 + t];
        p = tok * o;
    }
    red[t] = p; __syncthreads();
    for (int s = 128; s >= 1; s >>= 1) { if (t < s) red[t] += red[t + s]; __syncthreads(); }

    if (t == 0) {
        float lb    = 64.f * red[0] / (denom * denom);
        float clip  = acc[128], clipq = acc[129];
        float ent   = (1.f - clipq * __builtin_amdgcn_exp2f(-QQ * __builtin_amdgcn_logf(clip))) * 5.f;
        out[0] = 1e-3f * ent + 1e-3f * lb;
    }
}

extern "C" void kernel_launch(void* const* d_in, const int* in_sizes, int n_in,
                              void* d_out, int out_size, void* d_ws, size_t ws_size,
                              hipStream_t stream) {
    const float* G  = (const float*)d_in[0];
    const int*   am = (const int*)d_in[1];
    long long NE = in_sizes[0];
    long long N  = NE / 64;
    int maskN    = in_sizes[1];
    int layers   = (int)(N / (long long)maskN);
    int maskPow2 = ((maskN & (maskN - 1)) == 0) ? 1 : 0;
    float* acc = (float*)d_ws;   // 130 floats

    long long tiles = (N + 63) >> 6;
    int grid = (int)(tiles < 1024 ? tiles : 1024);

    // MEASUREMENT: run the main kernel twice with a wipe between. Output is
    // identical to a single run (pass 1 fully discarded); the dur_us delta vs
    // R3's single-launch 414us reveals T_moe, which top-5 counters cannot
    // (every moe dispatch is below the 157us fill cutoff). Same work every
    // call -- graph-capture safe.
    hipLaunchKernelGGL(zero_acc, dim3(1), dim3(256), 0, stream, acc);
    hipLaunchKernelGGL(moe_main, dim3(grid), dim3(256), 0, stream,
                       G, am, N, maskN, maskPow2, acc);
    hipLaunchKernelGGL(zero_acc, dim3(1), dim3(256), 0, stream, acc);
    hipLaunchKernelGGL(moe_main, dim3(grid), dim3(256), 0, stream,
                       G, am, N, maskN, maskPow2, acc);
    hipLaunchKernelGGL(finalize, dim3(1), dim3(256), 0, stream,
                       acc, am, maskN, layers, (float*)d_out);
}

// Round 6
// 390.831 us; speedup vs baseline: 1.2561x; 1.2561x over previous
//
#include <hip/hip_runtime.h>
#include <cstdint>

// DynMoleRouterLoss: gate_logits [N x 64] f32, attention_mask [maskN] i32 -> scalar f32.
// R6: thread-per-row via LDS transpose tile. R5 measured T_moe ~77-90us vs 41us HBM
// floor; R3's cost was 12 dependent ds_swizzle+lgkmcnt chains per row (butterflies).
// Now: stage 64 rows/wave coalesced (global->regs->LDS, XOR chunk swizzle c^(r&7):
// row b128 reads AND column b32 reads conflict-free, 16KB/wave, no pad), then each
// lane owns one full row in registers -- all reductions are in-register trees, zero
// cross-lane ops in the hot loop. Per-expert sums: write back w*m, column pass
// (lane=expert). Rare top-p path: wave-cooperative from the tile (~never taken).
// No __syncthreads in main loop (wave-private LDS). LDS 64KB/block -> 2 blocks/CU.
// acc layout in d_ws (floats): [0..63] m-weighted per-expert sums, [64..127]
// top-p corrections, [128] sum(clip(w)), [129] sum(clip(w)^1.2).

static constexpr float LOG2E = 1.4426950408889634f;
static constexpr float EPS   = 1e-5f;
static constexpr float EPSQ  = 1e-6f;     // (1e-5)^1.2
static constexpr float QQ    = 1.2f;

__global__ void zero_acc(float* __restrict__ a) {
    if (threadIdx.x < 130) a[threadIdx.x] = 0.f;
}

__global__ __launch_bounds__(256)
void moe_main(const float* __restrict__ G, const int* __restrict__ am,
              long long N, int maskN, int maskPow2, float* __restrict__ acc)
{
    __shared__ float4 T4[4096];            // 4 waves x 1024 chunks x 16B = 64 KB
    float* Tf = (float*)T4;

    const int t    = threadIdx.x;
    const int wv   = t >> 6;
    const int lane = t & 63;               // lane == row within wave-tile == expert in col pass
    const int rx   = lane & 7;             // row-read swizzle key
    const int lh   = lane >> 2;            // column-pass chunk of this expert
    const int l4   = lane & 3;
    const int wb4  = wv * 1024;            // float4 base of this wave's region
    const int wbF  = wv * 4096;            // float  base

    const float4* G4 = (const float4*)G;
    const long long tiles  = (N + 63) >> 6;
    const long long wslots = (long long)gridDim.x * 4;

    float ea = 0.f, clipA = 0.f, clipqA = 0.f;

    for (long long tl = (long long)blockIdx.x * 4 + wv; tl < tiles; tl += wslots) {
        const long long rb = tl << 6;

        // ---- stage: 16 coalesced float4 loads -> swizzled LDS (wave-private) ----
        float4 stg[16];
        #pragma unroll
        for (int k = 0; k < 16; ++k) {
            int f = k * 64 + lane;                   // flat chunk in tile
            long long srow = rb + (f >> 4);
            if (srow >= N) srow = N - 1;             // clamp (tail safety)
            stg[k] = G4[srow * 16 + (f & 15)];
        }
        #pragma unroll
        for (int k = 0; k < 16; ++k) {
            int f = k * 64 + lane;
            int r = f >> 4, c = f & 15;
            T4[wb4 + r * 16 + (c ^ (r & 7))] = stg[k];
        }

        // ---- this thread's row ----
        const bool rvalid = (rb + lane) < N;
        long long grow = rvalid ? (rb + lane) : (N - 1);
        int mi = maskPow2 ? (int)(grow & (long long)(maskN - 1))
                          : (int)(grow % (long long)maskN);
        float msc = rvalid ? (float)am[mi] : 0.f;

        float x[64];
        #pragma unroll
        for (int k = 0; k < 16; ++k) {
            float4 v = T4[wb4 + lane * 16 + (k ^ rx)];
            x[4*k+0] = v.x; x[4*k+1] = v.y; x[4*k+2] = v.z; x[4*k+3] = v.w;
        }

        // in-register max tree (depth 6, no cross-lane)
        float r32[32];
        #pragma unroll
        for (int i = 0; i < 32; ++i) r32[i] = fmaxf(x[i], x[i+32]);
        #pragma unroll
        for (int i = 0; i < 16; ++i) r32[i] = fmaxf(r32[i], r32[i+16]);
        #pragma unroll
        for (int i = 0; i < 8;  ++i) r32[i] = fmaxf(r32[i], r32[i+8]);
        #pragma unroll
        for (int i = 0; i < 4;  ++i) r32[i] = fmaxf(r32[i], r32[i+4]);
        float mxl = fmaxf(fmaxf(r32[0], r32[1]), fmaxf(r32[2], r32[3])) * LOG2E;

        // t_i (in x) and e_i
        float e[64];
        #pragma unroll
        for (int i = 0; i < 64; ++i) {
            x[i] = __fmaf_rn(x[i], LOG2E, -mxl);
            e[i] = __builtin_amdgcn_exp2f(x[i]);
        }
        // in-register sum tree -> z
        float s32[32];
        #pragma unroll
        for (int i = 0; i < 32; ++i) s32[i] = e[i] + e[i+32];
        #pragma unroll
        for (int i = 0; i < 16; ++i) s32[i] = s32[i] + s32[i+16];
        #pragma unroll
        for (int i = 0; i < 8;  ++i) s32[i] = s32[i] + s32[i+8];
        #pragma unroll
        for (int i = 0; i < 4;  ++i) s32[i] = s32[i] + s32[i+4];
        float z  = (s32[0] + s32[1]) + (s32[2] + s32[3]);

        float lz  = __builtin_amdgcn_logf(z);            // log2(z)
        float rz  = __builtin_amdgcn_exp2f(-lz);         // 1/z
        float zq  = __builtin_amdgcn_exp2f(-QQ * lz);    // z^-1.2
        float rzm = rz * msc;

        // pass 3: clip stats + write back w*m (swizzled)
        float rcA=0.f, rcB=0.f, rcC=0.f, rcD=0.f;
        float rqA=0.f, rqB=0.f, rqC=0.f, rqD=0.f;
        #pragma unroll
        for (int k = 0; k < 16; ++k) {
            float w0 = e[4*k+0]*rz, w1 = e[4*k+1]*rz, w2 = e[4*k+2]*rz, w3 = e[4*k+3]*rz;
            rcA += fmaxf(w0, EPS); rcB += fmaxf(w1, EPS);
            rcC += fmaxf(w2, EPS); rcD += fmaxf(w3, EPS);
            rqA += fmaxf(__builtin_amdgcn_exp2f(QQ*x[4*k+0])*zq, EPSQ);
            rqB += fmaxf(__builtin_amdgcn_exp2f(QQ*x[4*k+1])*zq, EPSQ);
            rqC += fmaxf(__builtin_amdgcn_exp2f(QQ*x[4*k+2])*zq, EPSQ);
            rqD += fmaxf(__builtin_amdgcn_exp2f(QQ*x[4*k+3])*zq, EPSQ);
            float4 wb = make_float4(e[4*k+0]*rzm, e[4*k+1]*rzm,
                                    e[4*k+2]*rzm, e[4*k+3]*rzm);
            T4[wb4 + lane * 16 + (k ^ rx)] = wb;
        }
        float rc  = (rcA + rcB) + (rcC + rcD);
        float rcq = (rqA + rqB) + (rqC + rqD);
        if (rvalid) { clipA += rc; clipqA += rcq; }

        // ---- rare top-p path (screened; ~never taken for N(0,1) logits) ----
        bool pre = rvalid && (msc != 0.f) && (rcq >= 0.699f);
        unsigned long long bal = __ballot(pre ? 1 : 0);
        if (bal) {
            float ent = (1.f - rcq * __builtin_amdgcn_exp2f(-QQ * __builtin_amdgcn_logf(rc))) * 5.f;
            bool flag = pre && (ent < 1.5f);
            bal = __ballot(flag ? 1 : 0);
            while (bal) {
                int r = __ffsll(bal) - 1; bal &= bal - 1;
                int r7 = r & 7;
                // this lane's expert value in row r (column-style read; m==1 here)
                float wl = Tf[wbF + r * 64 + ((lh ^ r7) << 2) + l4];
                int rank = 0; float cum = wl;
                #pragma unroll 4
                for (int j = 0; j < 64; ++j) {
                    float uj = Tf[wbF + r * 64 + (((j >> 2) ^ r7) << 2) + (j & 3)]; // broadcast
                    bool before = (uj > wl) || (uj == wl && j < lane);
                    rank += before ? 1 : 0;
                    cum  += before ? uj : 0.f;
                }
                if (cum > 0.75f && rank >= 2) atomicAdd(&acc[64 + lane], wl);
            }
        }

        // ---- column pass: lane == expert, sum w*m over the 64 rows ----
        #pragma unroll
        for (int r = 0; r < 64; ++r) {     // r&7 is compile-time per iteration
            ea += Tf[wbF + r * 64 + ((lh ^ (r & 7)) << 2) + l4];
        }
    }

    // ---- epilogue ----
    __syncthreads();                        // all waves done with their tile regions
    #pragma unroll
    for (int sh = 1; sh <= 32; sh <<= 1) {
        clipA  += __shfl_xor(clipA,  sh, 64);
        clipqA += __shfl_xor(clipqA, sh, 64);
    }
    Tf[wv * 64 + lane] = ea;
    if (lane == 0) { Tf[256 + wv] = clipA; Tf[260 + wv] = clipqA; }
    __syncthreads();
    if (t < 64) {
        float v = (Tf[t] + Tf[64 + t]) + (Tf[128 + t] + Tf[192 + t]);
        atomicAdd(&acc[t], v);
    }
    if (t == 0) {
        atomicAdd(&acc[128], (Tf[256] + Tf[257]) + (Tf[258] + Tf[259]));
        atomicAdd(&acc[129], (Tf[260] + Tf[261]) + (Tf[262] + Tf[263]));
    }
}

__global__ void finalize(const float* __restrict__ acc, const int* __restrict__ am,
                         int maskN, int layers, float* __restrict__ out) {
    __shared__ float red[256];
    int t = threadIdx.x;

    float ms = 0.f;
    for (int i = t; i < maskN; i += 256) ms += (float)am[i];
    red[t] = ms; __syncthreads();
    for (int s = 128; s >= 1; s >>= 1) { if (t < s) red[t] += red[t + s]; __syncthreads(); }
    float denom = red[0] * (float)layers;
    __syncthreads();

    float p = 0.f;
    if (t < 64) {
        float o   = acc[t];
        float tok = o - acc[64 + t];
        p = tok * o;
    }
    red[t] = p; __syncthreads();
    for (int s = 128; s >= 1; s >>= 1) { if (t < s) red[t] += red[t + s]; __syncthreads(); }

    if (t == 0) {
        float lb    = 64.f * red[0] / (denom * denom);
        float clip  = acc[128], clipq = acc[129];
        float ent   = (1.f - clipq * __builtin_amdgcn_exp2f(-QQ * __builtin_amdgcn_logf(clip))) * 5.f;
        out[0] = 1e-3f * ent + 1e-3f * lb;
    }
}

extern "C" void kernel_launch(void* const* d_in, const int* in_sizes, int n_in,
                              void* d_out, int out_size, void* d_ws, size_t ws_size,
                              hipStream_t stream) {
    const float* G  = (const float*)d_in[0];
    const int*   am = (const int*)d_in[1];
    long long NE = in_sizes[0];
    long long N  = NE / 64;
    int maskN    = in_sizes[1];
    int layers   = (int)(N / (long long)maskN);
    int maskPow2 = ((maskN & (maskN - 1)) == 0) ? 1 : 0;
    float* acc = (float*)d_ws;   // 130 floats

    long long tiles = (N + 63) >> 6;          // 64-row wave-tiles
    long long wantB = (tiles + 3) >> 2;       // 4 waves per block
    int grid = (int)(wantB < 1024 ? wantB : 1024);

    hipLaunchKernelGGL(zero_acc, dim3(1), dim3(256), 0, stream, acc);
    hipLaunchKernelGGL(moe_main, dim3(grid), dim3(256), 0, stream,
                       G, am, N, maskN, maskPow2, acc);
    hipLaunchKernelGGL(finalize, dim3(1), dim3(256), 0, stream,
                       acc, am, maskN, layers, (float*)d_out);
}